// Round 8
// baseline (881.546 us; speedup 1.0000x reference)
//
#include <hip/hip_runtime.h>
#include <hip/hip_bf16.h>

// Problem constants
#define TSEG 8
#define NBC 4          // clips
#define NBT 32         // B*T
#define CIN 256
#define CH 64
#define HIN 112
#define WIN_ 112
#define HO 56
#define WO 56
#define HPD 64
#define WPD 64
#define NSLOT 12       // circular B-row window slots

#define FRSZE ((size_t)(HPD * WPD * CH))    // 262144 bf16 elems per padded frame
#define ZF_U   147456
#define FR_U   (ZF_U + 262144)               // ushort offset of the 32 real frames
#define WS_TOTAL_BYTES ((size_t)(FR_U + 32 * 262144) * 2)   // 17,596,416 B

typedef __attribute__((ext_vector_type(8))) short bf16x8;
typedef __attribute__((ext_vector_type(4))) float f32x4;

__device__ __forceinline__ unsigned short f2bf(float f) {
    union { float f; unsigned u; } c; c.f = f;
    unsigned u = c.u + 0x7fffu + ((c.u >> 16) & 1u);
    return (unsigned short)(u >> 16);
}

// ---------------------------------------------------------------------------
// Weight prep: w[cout][ci][kh][kw] fp32 -> w''[tap][cout][ci] bf16 (RNE)
// ---------------------------------------------------------------------------
__global__ __launch_bounds__(256) void wprep_k(
    const float* __restrict__ w, unsigned short* __restrict__ wpp)
{
    int e = blockIdx.x * 256 + threadIdx.x;     // < 147456
    int cout = e / 2304;
    int rem  = e - cout * 2304;
    int ci   = rem / 9;
    int tap  = rem - ci * 9;
    wpp[((size_t)tap * 64 + cout) * 256 + ci] = f2bf(w[e]);
}

// ---------------------------------------------------------------------------
// Conv3x3 s2 p1 + BN + ReLU + per-pixel L2 norm, via bf16 MFMA implicit GEMM.
// Writes bf16 padded frames [bt][h+4][w+4][c].   (unchanged from R5)
// ---------------------------------------------------------------------------
__global__ __launch_bounds__(256) void conv_mfma_k(
    const float* __restrict__ x, const unsigned short* __restrict__ wpp,
    const float* __restrict__ gamma, const float* __restrict__ beta,
    const float* __restrict__ mean, const float* __restrict__ var,
    unsigned short* __restrict__ frames)
{
    __shared__ unsigned short in_lds[5 * 120 * 32];   // 38,400 B, swizzled
    __shared__ float sq[2][2][64];

    const int tid  = threadIdx.x;
    const int lane = tid & 63;
    const int wv   = tid >> 6;
    const int r    = wv >> 1;
    const int nh   = wv & 1;
    const int l15  = lane & 15;
    const int l4   = lane >> 4;
    const int hb   = blockIdx.x;
    const int bt   = blockIdx.y;

    const float* xb = x + (size_t)bt * (CIN * HIN * WIN_);

    f32x4 acc[4][2];
#pragma unroll
    for (int mt = 0; mt < 4; ++mt) {
        acc[mt][0] = (f32x4){0.f, 0.f, 0.f, 0.f};
        acc[mt][1] = (f32x4){0.f, 0.f, 0.f, 0.f};
    }

    int a_off[4][3];
#pragma unroll
    for (int mt = 0; mt < 4; ++mt) {
        int c = mt * 16 + l15; if (c > 55) c = 55;
#pragma unroll
        for (int kw = 0; kw < 3; ++kw) {
            int col = 2 * c + kw;
            int ba  = col * 64 + l4 * 16;
            ba ^= ((col >> 1) & 7) << 4;
            a_off[mt][kw] = ba;
        }
    }

    const unsigned short* bptr0 = wpp + ((size_t)(nh * 32 + l15) * 256 + l4 * 8);
    const unsigned short* bptr1 = wpp + ((size_t)(nh * 32 + 16 + l15) * 256 + l4 * 8);

    const int ih0 = 4 * hb - 1;

    for (int cb = 0; cb < 8; ++cb) {
        __syncthreads();
#pragma unroll
        for (int j = 0; j < 5; ++j) {
            const int jj  = wv + j * 4;
            const int row = jj >> 2, cig = jj & 3;
            const int ih  = ih0 + row;
            const int ihc = ih < 0 ? 0 : (ih > 111 ? 111 : ih);
            const float* xr = xb + ((size_t)(cb * 32 + cig * 8) * HIN + ihc) * WIN_;
            const bool rowin = (ih >= 0) && (ih < HIN);
#pragma unroll
            for (int p = 0; p < 2; ++p) {
                const int col = lane + p * 64;
                if (col < 113) {
                    const int iw  = col - 1;
                    const int iwc = iw < 0 ? 0 : iw;
                    const bool inb = rowin && (iw >= 0);
                    unsigned pk[4];
#pragma unroll
                    for (int q = 0; q < 4; ++q) {
                        float v0 = xr[(size_t)(2 * q) * HIN * WIN_ + iwc];
                        float v1 = xr[(size_t)(2 * q + 1) * HIN * WIN_ + iwc];
                        v0 = inb ? v0 : 0.f;
                        v1 = inb ? v1 : 0.f;
                        union { float f; unsigned u; } c0, c1; c0.f = v0; c1.f = v1;
                        unsigned u0 = c0.u + 0x7fffu + ((c0.u >> 16) & 1u);
                        unsigned u1 = c1.u + 0x7fffu + ((c1.u >> 16) & 1u);
                        pk[q] = (u0 >> 16) | (u1 & 0xffff0000u);
                    }
                    int ba = (row * 120 + col) * 64 + cig * 16;
                    ba ^= ((col >> 1) & 7) << 4;
                    *(uint4*)((char*)in_lds + ba) = make_uint4(pk[0], pk[1], pk[2], pk[3]);
                }
            }
        }
        __syncthreads();

        const int rowb = (2 * r) * 7680;
#pragma unroll
        for (int kh = 0; kh < 3; ++kh) {
            const int rb = rowb + kh * 7680;
#pragma unroll
            for (int kw = 0; kw < 3; ++kw) {
                const int tap = kh * 3 + kw;
                const bf16x8 bf0 = *(const bf16x8*)(bptr0 + tap * 16384 + cb * 32);
                const bf16x8 bf1 = *(const bf16x8*)(bptr1 + tap * 16384 + cb * 32);
#pragma unroll
                for (int mt = 0; mt < 4; ++mt) {
                    const bf16x8 af = *(const bf16x8*)((const char*)in_lds + (rb + a_off[mt][kw]));
                    acc[mt][0] = __builtin_amdgcn_mfma_f32_16x16x32_bf16(af, bf0, acc[mt][0], 0, 0, 0);
                    acc[mt][1] = __builtin_amdgcn_mfma_f32_16x16x32_bf16(af, bf1, acc[mt][1], 0, 0, 0);
                }
            }
        }
    }

    const int cout0 = nh * 32 + l15;
    const int cout1 = cout0 + 16;
    const float sc0 = gamma[cout0] * rsqrtf(var[cout0] + 1e-5f);
    const float bb0 = beta[cout0] - mean[cout0] * sc0;
    const float sc1 = gamma[cout1] * rsqrtf(var[cout1] + 1e-5f);
    const float bb1 = beta[cout1] - mean[cout1] * sc1;

    float yv[4][2][4];
    float ssr[4][4];
#pragma unroll
    for (int mt = 0; mt < 4; ++mt) {
#pragma unroll
        for (int reg = 0; reg < 4; ++reg) {
            float y0 = fmaxf(fmaf(acc[mt][0][reg], sc0, bb0), 0.f);
            float y1 = fmaxf(fmaf(acc[mt][1][reg], sc1, bb1), 0.f);
            yv[mt][0][reg] = y0; yv[mt][1][reg] = y1;
            float ss = y0 * y0 + y1 * y1;
            ss += __shfl_xor(ss, 1);
            ss += __shfl_xor(ss, 2);
            ss += __shfl_xor(ss, 4);
            ss += __shfl_xor(ss, 8);
            ssr[mt][reg] = ss;
        }
    }
    if (l15 == 0) {
#pragma unroll
        for (int mt = 0; mt < 4; ++mt)
#pragma unroll
            for (int reg = 0; reg < 4; ++reg)
                sq[r][nh][mt * 16 + l4 * 4 + reg] = ssr[mt][reg];
    }
    __syncthreads();

    const int h = 2 * hb + r;
    unsigned short* fdst = frames + (size_t)bt * FRSZE + (size_t)(h + 4) * WPD * CH;
#pragma unroll
    for (int mt = 0; mt < 4; ++mt) {
#pragma unroll
        for (int reg = 0; reg < 4; ++reg) {
            const int c = mt * 16 + l4 * 4 + reg;
            if (c < 56) {
                const float tot = sq[r][0][c] + sq[r][1][c];
                const float inv = rsqrtf(tot + 1e-6f);
                unsigned short* dp = fdst + (size_t)(c + 4) * CH;
                dp[cout0] = f2bf(yv[mt][0][reg] * inv);
                dp[cout1] = f2bf(yv[mt][1][reg] * inv);
            }
        }
    }
}

// ---------------------------------------------------------------------------
// Kernel 2 (R8): rolling-window correlation.
// Block = 128 thr (2 waves) owns (b,t,l) x 14-row h-strip; 7 steps of h+=2,
// wave w computes h = h0+2s+w. B-rows live in a 12-slot circular LDS window
// (XOR-swizzled); each step stages 2 new rows (load early, ds_write late,
// raw s_barrier). B-traffic per unit: 0.70 MB instead of 4 MB.
// ---------------------------------------------------------------------------
__global__ __launch_bounds__(128) void corr_roll_k(
    const unsigned short* __restrict__ frames, float* __restrict__ out)
{
    __shared__ unsigned short win[NSLOT * 4096];   // 98,304 B
    __shared__ float so[2][56 * 84];               // 37,632 B

    const int tid  = threadIdx.x;
    const int lane = tid & 63;
    const int wv   = tid >> 6;
    const int l15  = lane & 15;
    const int l4   = lane >> 4;

    const int bid   = blockIdx.x;      // 0..639
    const int unit  = bid >> 2;        // 0..159
    const int strip = bid & 3;
    const int b  = unit / 40;
    const int rm = unit - b * 40;
    const int t  = rm / 5;
    const int l  = rm - t * 5;
    const int h0 = strip * 14;
    const int bt = b * TSEG + t;

    float* obase = out + (size_t)(bt * HO) * (WO * 405) + l * 81;

    const int f = t + l;               // padded frame index 0..11
    if (f < 2 || f > 9) {
        // temporal pad: zeros (wave wv writes rows h0 + 2i + wv)
#pragma unroll
        for (int i = 0; i < 7; ++i) {
            const int h = h0 + 2 * i + wv;
            float* ob = obase + (size_t)h * (WO * 405);
#pragma unroll 4
            for (int w = 0; w < 56; ++w) {
                float* orow = ob + (size_t)w * 405;
                orow[lane] = 0.f;
                if (lane < 17) orow[lane + 64] = 0.f;
            }
        }
        return;
    }

    const unsigned short* fb = frames + (size_t)(b * TSEG + f - 2) * FRSZE;
    const unsigned short* cf = frames + (size_t)bt * FRSZE;

    // staging ds_write offsets: chunk c = q*64+lane at byte c*16, swizzled
    int woff[8];
#pragma unroll
    for (int q = 0; q < 8; ++q)
        woff[q] = (q * 1024 + lane * 16) ^ (((lane >> 3) & 7) << 4);

    // window read offsets: px = n*16+l15, halves hf, bytes px*128+hf*64+l4*16
    int roff[4][2];
#pragma unroll
    for (int n = 0; n < 4; ++n) {
        const int px = n * 16 + l15;
#pragma unroll
        for (int hf = 0; hf < 2; ++hf)
            roff[n][hf] = (px * 128 + hf * 64 + l4 * 16) ^ ((px & 7) << 4);
    }

    const int PM[7] = {0, 0, 1, 1, 2, 2, 3};
    const int PN[7] = {0, 1, 1, 2, 2, 3, 3};

#define STAGE_LOAD(g, row) { \
    const unsigned short* zr = fb + (size_t)(row) * 4096 + lane * 8; \
    _Pragma("unroll") \
    for (int q = 0; q < 8; ++q) g[q] = *(const uint4*)(zr + q * 512); }

#define STAGE_WRITE(g, row) { \
    char* wb = (char*)win + ((row) % NSLOT) * 8192; \
    _Pragma("unroll") \
    for (int q = 0; q < 8; ++q) *(uint4*)(wb + woff[q]) = g[q]; }

#define LOADA(af, hh) { \
    const unsigned short* yr = cf + (size_t)((hh) + 4) * 4096; \
    _Pragma("unroll") \
    for (int m = 0; m < 4; ++m) { \
        int w = (m << 4) + l15; if (w > 55) w = 55; \
        const unsigned short* ap = yr + (w + 4) * 64 + (l4 << 3); \
        af[m][0] = *(const bf16x8*)(ap); \
        af[m][1] = *(const bf16x8*)(ap + 32); } }

#define COMPH(af, hh) { \
    float* sw = so[wv]; \
    const int hm = (hh) % NSLOT; \
    _Pragma("unroll") \
    for (int u = 0; u < 9; ++u) { \
        int sl = hm + u; if (sl >= NSLOT) sl -= NSLOT; \
        const char* rb = (const char*)win + sl * 8192; \
        bf16x8 bfr[4][2]; \
        _Pragma("unroll") \
        for (int n = 0; n < 4; ++n) { \
            bfr[n][0] = *(const bf16x8*)(rb + roff[n][0]); \
            bfr[n][1] = *(const bf16x8*)(rb + roff[n][1]); } \
        f32x4 acc[7]; \
        _Pragma("unroll") \
        for (int i = 0; i < 7; ++i) acc[i] = (f32x4){0.f, 0.f, 0.f, 0.f}; \
        _Pragma("unroll") \
        for (int i = 0; i < 7; ++i) { \
            acc[i] = __builtin_amdgcn_mfma_f32_16x16x32_bf16(af[PM[i]][0], bfr[PN[i]][0], acc[i], 0, 0, 0); \
            acc[i] = __builtin_amdgcn_mfma_f32_16x16x32_bf16(af[PM[i]][1], bfr[PN[i]][1], acc[i], 0, 0, 0); } \
        _Pragma("unroll") \
        for (int i = 0; i < 7; ++i) { \
            const int zc = (PN[i] << 4) + l15; \
            const int w0 = (PM[i] << 4) + (l4 << 2); \
            _Pragma("unroll") \
            for (int rr = 0; rr < 4; ++rr) { \
                const int w = w0 + rr; \
                const int v = zc - w; \
                if (w < 56 && (unsigned)v <= 8u) \
                    sw[w * 84 + u * 9 + v] = acc[i][rr]; } } } }

#define STORES(hh) { \
    float* ob = obase + (size_t)(hh) * (WO * 405); \
    const float* sb = so[wv]; \
    _Pragma("unroll 4") \
    for (int w = 0; w < 56; ++w) { \
        const float* sr = sb + w * 84; \
        float* orow = ob + (size_t)w * 405; \
        orow[lane] = sr[lane]; \
        if (lane < 17) orow[lane + 64] = sr[lane + 64]; } }

    // ---- initial fill: rows h0..h0+9; wave wv stages rows h0+wv+2k ----
    bf16x8 A0[4][2], A1[4][2];
    {
        uint4 ga[8], gb[8];
        STAGE_LOAD(ga, h0 + wv + 0);
        STAGE_LOAD(gb, h0 + wv + 2);
        STAGE_WRITE(ga, h0 + wv + 0);
        STAGE_LOAD(ga, h0 + wv + 4);
        STAGE_WRITE(gb, h0 + wv + 2);
        STAGE_LOAD(gb, h0 + wv + 6);
        STAGE_WRITE(ga, h0 + wv + 4);
        STAGE_LOAD(ga, h0 + wv + 8);
        STAGE_WRITE(gb, h0 + wv + 6);
        STAGE_WRITE(ga, h0 + wv + 8);
        LOADA(A0, h0 + wv);
        asm volatile("s_waitcnt lgkmcnt(0)" ::: "memory");
        __builtin_amdgcn_sched_barrier(0);
        __builtin_amdgcn_s_barrier();
    }

    uint4 gs[8];
#define STEP(s, AC, AN) { \
    const int h_ = h0 + 2 * (s) + wv; \
    if ((s) < 6) { \
        STAGE_LOAD(gs, h0 + 2 * (s) + 10 + wv); \
        LOADA(AN, h0 + 2 * ((s) + 1) + wv); \
    } \
    COMPH(AC, h_); \
    if ((s) < 6) { \
        STAGE_WRITE(gs, h0 + 2 * (s) + 10 + wv); \
        asm volatile("s_waitcnt lgkmcnt(0)" ::: "memory"); \
        __builtin_amdgcn_sched_barrier(0); \
        __builtin_amdgcn_s_barrier(); \
    } \
    STORES(h_); }

    STEP(0, A0, A1);
    STEP(1, A1, A0);
    STEP(2, A0, A1);
    STEP(3, A1, A0);
    STEP(4, A0, A1);
    STEP(5, A1, A0);
    STEP(6, A0, A1);

#undef STEP
#undef STORES
#undef COMPH
#undef LOADA
#undef STAGE_WRITE
#undef STAGE_LOAD
}

// ---------------------------------------------------------------------------
extern "C" void kernel_launch(void* const* d_in, const int* in_sizes, int n_in,
                              void* d_out, int out_size, void* d_ws, size_t ws_size,
                              hipStream_t stream)
{
    const float* x     = (const float*)d_in[0];
    const float* wgt   = (const float*)d_in[1];
    const float* gamma = (const float*)d_in[2];
    const float* beta  = (const float*)d_in[3];
    const float* mean  = (const float*)d_in[4];
    const float* var   = (const float*)d_in[5];
    float* out = (float*)d_out;

    unsigned short* wpp    = (unsigned short*)d_ws;
    unsigned short* frames = wpp + FR_U;

    if (ws_size < WS_TOTAL_BYTES) return;

    hipMemsetAsync(d_ws, 0, WS_TOTAL_BYTES, stream);
    wprep_k<<<dim3(576), 256, 0, stream>>>(wgt, wpp);
    conv_mfma_k<<<dim3(28, NBT), 256, 0, stream>>>(x, wpp, gamma, beta, mean, var, frames);
    corr_roll_k<<<dim3(640), 128, 0, stream>>>(frames, out);
}

// Round 9
// 300.051 us; speedup vs baseline: 2.9380x; 2.9380x over previous
//
#include <hip/hip_runtime.h>
#include <hip/hip_bf16.h>

// Problem constants
#define TSEG 8
#define NBC 4          // clips
#define NBT 32         // B*T
#define CIN 256
#define CH 64
#define HIN 112
#define WIN_ 112
#define HO 56
#define WO 56
#define HPD 64
#define WPD 64

#define FRSZE ((size_t)(HPD * WPD * CH))    // 262144 bf16 elems per padded frame
#define ZF_U   147456
#define FR_U   (ZF_U + 262144)               // ushort offset of the 32 real frames
#define WS_TOTAL_BYTES ((size_t)(FR_U + 32 * 262144) * 2)   // 17,596,416 B

typedef __attribute__((ext_vector_type(8))) short bf16x8;
typedef __attribute__((ext_vector_type(4))) float f32x4;

__device__ __forceinline__ unsigned short f2bf(float f) {
    union { float f; unsigned u; } c; c.f = f;
    unsigned u = c.u + 0x7fffu + ((c.u >> 16) & 1u);
    return (unsigned short)(u >> 16);
}

// ---------------------------------------------------------------------------
// Weight prep: w[cout][ci][kh][kw] fp32 -> w''[tap][cout][ci] bf16 (RNE)
// ---------------------------------------------------------------------------
__global__ __launch_bounds__(256) void wprep_k(
    const float* __restrict__ w, unsigned short* __restrict__ wpp)
{
    int e = blockIdx.x * 256 + threadIdx.x;     // < 147456
    int cout = e / 2304;
    int rem  = e - cout * 2304;
    int ci   = rem / 9;
    int tap  = rem - ci * 9;
    wpp[((size_t)tap * 64 + cout) * 256 + ci] = f2bf(w[e]);
}

// ---------------------------------------------------------------------------
// Conv3x3 s2 p1 + BN + ReLU + per-pixel L2 norm, via bf16 MFMA implicit GEMM.
// Writes bf16 padded frames [bt][h+4][w+4][c].   (unchanged from R5)
// ---------------------------------------------------------------------------
__global__ __launch_bounds__(256) void conv_mfma_k(
    const float* __restrict__ x, const unsigned short* __restrict__ wpp,
    const float* __restrict__ gamma, const float* __restrict__ beta,
    const float* __restrict__ mean, const float* __restrict__ var,
    unsigned short* __restrict__ frames)
{
    __shared__ unsigned short in_lds[5 * 120 * 32];   // 38,400 B, swizzled
    __shared__ float sq[2][2][64];

    const int tid  = threadIdx.x;
    const int lane = tid & 63;
    const int wv   = tid >> 6;
    const int r    = wv >> 1;
    const int nh   = wv & 1;
    const int l15  = lane & 15;
    const int l4   = lane >> 4;
    const int hb   = blockIdx.x;
    const int bt   = blockIdx.y;

    const float* xb = x + (size_t)bt * (CIN * HIN * WIN_);

    f32x4 acc[4][2];
#pragma unroll
    for (int mt = 0; mt < 4; ++mt) {
        acc[mt][0] = (f32x4){0.f, 0.f, 0.f, 0.f};
        acc[mt][1] = (f32x4){0.f, 0.f, 0.f, 0.f};
    }

    int a_off[4][3];
#pragma unroll
    for (int mt = 0; mt < 4; ++mt) {
        int c = mt * 16 + l15; if (c > 55) c = 55;
#pragma unroll
        for (int kw = 0; kw < 3; ++kw) {
            int col = 2 * c + kw;
            int ba  = col * 64 + l4 * 16;
            ba ^= ((col >> 1) & 7) << 4;
            a_off[mt][kw] = ba;
        }
    }

    const unsigned short* bptr0 = wpp + ((size_t)(nh * 32 + l15) * 256 + l4 * 8);
    const unsigned short* bptr1 = wpp + ((size_t)(nh * 32 + 16 + l15) * 256 + l4 * 8);

    const int ih0 = 4 * hb - 1;

    for (int cb = 0; cb < 8; ++cb) {
        __syncthreads();
#pragma unroll
        for (int j = 0; j < 5; ++j) {
            const int jj  = wv + j * 4;
            const int row = jj >> 2, cig = jj & 3;
            const int ih  = ih0 + row;
            const int ihc = ih < 0 ? 0 : (ih > 111 ? 111 : ih);
            const float* xr = xb + ((size_t)(cb * 32 + cig * 8) * HIN + ihc) * WIN_;
            const bool rowin = (ih >= 0) && (ih < HIN);
#pragma unroll
            for (int p = 0; p < 2; ++p) {
                const int col = lane + p * 64;
                if (col < 113) {
                    const int iw  = col - 1;
                    const int iwc = iw < 0 ? 0 : iw;
                    const bool inb = rowin && (iw >= 0);
                    unsigned pk[4];
#pragma unroll
                    for (int q = 0; q < 4; ++q) {
                        float v0 = xr[(size_t)(2 * q) * HIN * WIN_ + iwc];
                        float v1 = xr[(size_t)(2 * q + 1) * HIN * WIN_ + iwc];
                        v0 = inb ? v0 : 0.f;
                        v1 = inb ? v1 : 0.f;
                        union { float f; unsigned u; } c0, c1; c0.f = v0; c1.f = v1;
                        unsigned u0 = c0.u + 0x7fffu + ((c0.u >> 16) & 1u);
                        unsigned u1 = c1.u + 0x7fffu + ((c1.u >> 16) & 1u);
                        pk[q] = (u0 >> 16) | (u1 & 0xffff0000u);
                    }
                    int ba = (row * 120 + col) * 64 + cig * 16;
                    ba ^= ((col >> 1) & 7) << 4;
                    *(uint4*)((char*)in_lds + ba) = make_uint4(pk[0], pk[1], pk[2], pk[3]);
                }
            }
        }
        __syncthreads();

        const int rowb = (2 * r) * 7680;
#pragma unroll
        for (int kh = 0; kh < 3; ++kh) {
            const int rb = rowb + kh * 7680;
#pragma unroll
            for (int kw = 0; kw < 3; ++kw) {
                const int tap = kh * 3 + kw;
                const bf16x8 bf0 = *(const bf16x8*)(bptr0 + tap * 16384 + cb * 32);
                const bf16x8 bf1 = *(const bf16x8*)(bptr1 + tap * 16384 + cb * 32);
#pragma unroll
                for (int mt = 0; mt < 4; ++mt) {
                    const bf16x8 af = *(const bf16x8*)((const char*)in_lds + (rb + a_off[mt][kw]));
                    acc[mt][0] = __builtin_amdgcn_mfma_f32_16x16x32_bf16(af, bf0, acc[mt][0], 0, 0, 0);
                    acc[mt][1] = __builtin_amdgcn_mfma_f32_16x16x32_bf16(af, bf1, acc[mt][1], 0, 0, 0);
                }
            }
        }
    }

    const int cout0 = nh * 32 + l15;
    const int cout1 = cout0 + 16;
    const float sc0 = gamma[cout0] * rsqrtf(var[cout0] + 1e-5f);
    const float bb0 = beta[cout0] - mean[cout0] * sc0;
    const float sc1 = gamma[cout1] * rsqrtf(var[cout1] + 1e-5f);
    const float bb1 = beta[cout1] - mean[cout1] * sc1;

    float yv[4][2][4];
    float ssr[4][4];
#pragma unroll
    for (int mt = 0; mt < 4; ++mt) {
#pragma unroll
        for (int reg = 0; reg < 4; ++reg) {
            float y0 = fmaxf(fmaf(acc[mt][0][reg], sc0, bb0), 0.f);
            float y1 = fmaxf(fmaf(acc[mt][1][reg], sc1, bb1), 0.f);
            yv[mt][0][reg] = y0; yv[mt][1][reg] = y1;
            float ss = y0 * y0 + y1 * y1;
            ss += __shfl_xor(ss, 1);
            ss += __shfl_xor(ss, 2);
            ss += __shfl_xor(ss, 4);
            ss += __shfl_xor(ss, 8);
            ssr[mt][reg] = ss;
        }
    }
    if (l15 == 0) {
#pragma unroll
        for (int mt = 0; mt < 4; ++mt)
#pragma unroll
            for (int reg = 0; reg < 4; ++reg)
                sq[r][nh][mt * 16 + l4 * 4 + reg] = ssr[mt][reg];
    }
    __syncthreads();

    const int h = 2 * hb + r;
    unsigned short* fdst = frames + (size_t)bt * FRSZE + (size_t)(h + 4) * WPD * CH;
#pragma unroll
    for (int mt = 0; mt < 4; ++mt) {
#pragma unroll
        for (int reg = 0; reg < 4; ++reg) {
            const int c = mt * 16 + l4 * 4 + reg;
            if (c < 56) {
                const float tot = sq[r][0][c] + sq[r][1][c];
                const float inv = rsqrtf(tot + 1e-6f);
                unsigned short* dp = fdst + (size_t)(c + 4) * CH;
                dp[cout0] = f2bf(yv[mt][0][reg] * inv);
                dp[cout1] = f2bf(yv[mt][1][reg] * inv);
            }
        }
    }
}

// ---------------------------------------------------------------------------
// Kernel 2 (R9): windowed correlation, h-PAIR blocks + per-u mini-slab.
// One 64-thread block per (b,t,l,h-pair). Rows h0,h0+1 share B-rows: row r
// serves (h0,u=r) and (h1,u=r-1) -> B traffic ~halved vs R5.
// After each (h,u) Gram: extract band into a 56x12 LDS mini-slab (stride 12
// => 2-way ds_write conflicts ~free), then immediately store 56 runs of 9
// contiguous floats (lane->(w,v)=(lane/9,lane%9), slab read lane-linear).
// LDS total 5.4 KB -> ~12 blocks/CU. No barriers. No grid swizzle.
// ---------------------------------------------------------------------------
#define SSTR 12
__global__ __launch_bounds__(64) void corr_pair_k(
    const unsigned short* __restrict__ frames, float* __restrict__ out)
{
    __shared__ float so[2][56 * SSTR];     // 5,376 B

    const int lane = threadIdx.x;
    const int l15  = lane & 15;
    const int l4   = lane >> 4;
    const int w7   = lane / 9;             // 0..7 (lane 63 -> 7, dup row)
    const int v9   = lane - w7 * 9;        // 0..8

    const int hp  = blockIdx.x;            // 0..27
    const int tl  = blockIdx.y;            // 0..39
    const int b   = blockIdx.z;
    const int t   = tl / 5, l = tl - 5 * t;
    const int h0  = hp * 2;
    const int bt  = b * TSEG + t;

    float* ob0 = out + (size_t)(bt * HO + h0) * (WO * 405) + l * 81;

    const int f = t + l;                   // padded frame index 0..11
    if (f < 2 || f > 9) {
        // temporal pad: output is exactly zero
#pragma unroll
        for (int hh = 0; hh < 2; ++hh) {
            float* ob = ob0 + (size_t)hh * (WO * 405);
#pragma unroll 4
            for (int w = 0; w < 56; ++w) {
                float* orow = ob + (size_t)w * 405;
                orow[lane] = 0.f;
                if (lane < 17) orow[lane + 64] = 0.f;
            }
        }
        return;
    }

    // A fragments: Y[w][c] for rows h0 and h0+1
    bf16x8 af[2][4][2];
#pragma unroll
    for (int hh = 0; hh < 2; ++hh) {
        const unsigned short* yrow = frames + (size_t)bt * FRSZE
                                   + (size_t)(h0 + hh + 4) * (WPD * CH);
#pragma unroll
        for (int m = 0; m < 4; ++m) {
            int w = (m << 4) + l15; if (w > 55) w = 55;  // clamp (masked later)
            const unsigned short* ap = yrow + (size_t)(w + 4) * CH + (l4 << 3);
            af[hh][m][0] = *(const bf16x8*)(ap);
            af[hh][m][1] = *(const bf16x8*)(ap + 32);
        }
    }

    const unsigned short* zb = frames + (size_t)(b * TSEG + f - 2) * FRSZE
                             + (size_t)h0 * (WPD * CH);

    const int PM[7] = {0, 0, 1, 1, 2, 2, 3};
    const int PN[7] = {0, 1, 1, 2, 2, 3, 3};

#define LOADB(buf, rr) { \
    const unsigned short* zr = zb + (size_t)(rr) * (WPD * CH); \
    _Pragma("unroll") \
    for (int n = 0; n < 4; ++n) { \
        const unsigned short* bp = zr + (size_t)((n << 4) + l15) * CH + (l4 << 3); \
        buf[n][0] = *(const bf16x8*)(bp); \
        buf[n][1] = *(const bf16x8*)(bp + 32); } }

// compute Gram for (hh, uu), extract band to mini-slab, store immediately
#define CS(buf, hh, uu) { \
    f32x4 acc[7]; \
    _Pragma("unroll") \
    for (int i = 0; i < 7; ++i) acc[i] = (f32x4){0.f, 0.f, 0.f, 0.f}; \
    _Pragma("unroll") \
    for (int i = 0; i < 7; ++i) { \
        acc[i] = __builtin_amdgcn_mfma_f32_16x16x32_bf16(af[hh][PM[i]][0], buf[PN[i]][0], acc[i], 0, 0, 0); \
        acc[i] = __builtin_amdgcn_mfma_f32_16x16x32_bf16(af[hh][PM[i]][1], buf[PN[i]][1], acc[i], 0, 0, 0); } \
    _Pragma("unroll") \
    for (int i = 0; i < 7; ++i) { \
        const int zc = (PN[i] << 4) + l15; \
        const int w0 = (PM[i] << 4) + (l4 << 2); \
        _Pragma("unroll") \
        for (int rr2 = 0; rr2 < 4; ++rr2) { \
            const int w = w0 + rr2; \
            const int v = zc - w; \
            if (w < 56 && (unsigned)v <= 8u) \
                so[hh][w * SSTR + v] = acc[i][rr2]; } } \
    { \
        float* obh = ob0 + (size_t)(hh) * (WO * 405) + (uu) * 9; \
        _Pragma("unroll") \
        for (int wb = 0; wb < 8; ++wb) { \
            const int w = wb * 7 + w7; \
            if (w < 56) obh[(size_t)w * 405 + v9] = so[hh][w * SSTR + v9]; \
        } \
    } }

    // rolling schedule: B row r serves (h0, u=r) and (h1, u=r-1)
    bf16x8 b0[4][2], b1[4][2], b2[4][2];
    LOADB(b0, 0); LOADB(b1, 1); LOADB(b2, 2);
    CS(b0, 0, 0);                    LOADB(b0, 3);
    CS(b1, 0, 1); CS(b1, 1, 0);      LOADB(b1, 4);
    CS(b2, 0, 2); CS(b2, 1, 1);      LOADB(b2, 5);
    CS(b0, 0, 3); CS(b0, 1, 2);      LOADB(b0, 6);
    CS(b1, 0, 4); CS(b1, 1, 3);      LOADB(b1, 7);
    CS(b2, 0, 5); CS(b2, 1, 4);      LOADB(b2, 8);
    CS(b0, 0, 6); CS(b0, 1, 5);      LOADB(b0, 9);
    CS(b1, 0, 7); CS(b1, 1, 6);
    CS(b2, 0, 8); CS(b2, 1, 7);
    CS(b0, 1, 8);

#undef CS
#undef LOADB
}

// ---------------------------------------------------------------------------
extern "C" void kernel_launch(void* const* d_in, const int* in_sizes, int n_in,
                              void* d_out, int out_size, void* d_ws, size_t ws_size,
                              hipStream_t stream)
{
    const float* x     = (const float*)d_in[0];
    const float* wgt   = (const float*)d_in[1];
    const float* gamma = (const float*)d_in[2];
    const float* beta  = (const float*)d_in[3];
    const float* mean  = (const float*)d_in[4];
    const float* var   = (const float*)d_in[5];
    float* out = (float*)d_out;

    unsigned short* wpp    = (unsigned short*)d_ws;
    unsigned short* frames = wpp + FR_U;

    if (ws_size < WS_TOTAL_BYTES) return;

    hipMemsetAsync(d_ws, 0, WS_TOTAL_BYTES, stream);
    wprep_k<<<dim3(576), 256, 0, stream>>>(wgt, wpp);
    conv_mfma_k<<<dim3(28, NBT), 256, 0, stream>>>(x, wpp, gamma, beta, mean, var, frames);
    corr_pair_k<<<dim3(28, 40, NBC), 64, 0, stream>>>(frames, out);
}

// Round 10
// 278.476 us; speedup vs baseline: 3.1656x; 1.0775x over previous
//
#include <hip/hip_runtime.h>
#include <hip/hip_bf16.h>

// Problem constants
#define TSEG 8
#define NBC 4          // clips
#define NBT 32         // B*T
#define CIN 256
#define CH 64
#define HIN 112
#define WIN_ 112
#define HO 56
#define WO 56
#define HPD 64
#define WPD 64

#define FRSZE ((size_t)(HPD * WPD * CH))    // 262144 bf16 elems per padded frame
#define ZF_U   147456
#define FR_U   (ZF_U + 262144)               // ushort offset of the 32 real frames
#define WS_TOTAL_BYTES ((size_t)(FR_U + 32 * 262144) * 2)   // 17,596,416 B

typedef __attribute__((ext_vector_type(8))) short bf16x8;
typedef __attribute__((ext_vector_type(4))) float f32x4;

__device__ __forceinline__ unsigned short f2bf(float f) {
    union { float f; unsigned u; } c; c.f = f;
    unsigned u = c.u + 0x7fffu + ((c.u >> 16) & 1u);
    return (unsigned short)(u >> 16);
}

// ---------------------------------------------------------------------------
// Weight prep: w[cout][ci][kh][kw] fp32 -> w''[tap][cout][ci] bf16 (RNE)
// ---------------------------------------------------------------------------
__global__ __launch_bounds__(256) void wprep_k(
    const float* __restrict__ w, unsigned short* __restrict__ wpp)
{
    int e = blockIdx.x * 256 + threadIdx.x;     // < 147456
    int cout = e / 2304;
    int rem  = e - cout * 2304;
    int ci   = rem / 9;
    int tap  = rem - ci * 9;
    wpp[((size_t)tap * 64 + cout) * 256 + ci] = f2bf(w[e]);
}

// ---------------------------------------------------------------------------
// Conv3x3 s2 p1 + BN + ReLU + per-pixel L2 norm, via bf16 MFMA implicit GEMM.
// Writes bf16 padded frames [bt][h+4][w+4][c].   (unchanged from R5)
// ---------------------------------------------------------------------------
__global__ __launch_bounds__(256) void conv_mfma_k(
    const float* __restrict__ x, const unsigned short* __restrict__ wpp,
    const float* __restrict__ gamma, const float* __restrict__ beta,
    const float* __restrict__ mean, const float* __restrict__ var,
    unsigned short* __restrict__ frames)
{
    __shared__ unsigned short in_lds[5 * 120 * 32];   // 38,400 B, swizzled
    __shared__ float sq[2][2][64];

    const int tid  = threadIdx.x;
    const int lane = tid & 63;
    const int wv   = tid >> 6;
    const int r    = wv >> 1;
    const int nh   = wv & 1;
    const int l15  = lane & 15;
    const int l4   = lane >> 4;
    const int hb   = blockIdx.x;
    const int bt   = blockIdx.y;

    const float* xb = x + (size_t)bt * (CIN * HIN * WIN_);

    f32x4 acc[4][2];
#pragma unroll
    for (int mt = 0; mt < 4; ++mt) {
        acc[mt][0] = (f32x4){0.f, 0.f, 0.f, 0.f};
        acc[mt][1] = (f32x4){0.f, 0.f, 0.f, 0.f};
    }

    int a_off[4][3];
#pragma unroll
    for (int mt = 0; mt < 4; ++mt) {
        int c = mt * 16 + l15; if (c > 55) c = 55;
#pragma unroll
        for (int kw = 0; kw < 3; ++kw) {
            int col = 2 * c + kw;
            int ba  = col * 64 + l4 * 16;
            ba ^= ((col >> 1) & 7) << 4;
            a_off[mt][kw] = ba;
        }
    }

    const unsigned short* bptr0 = wpp + ((size_t)(nh * 32 + l15) * 256 + l4 * 8);
    const unsigned short* bptr1 = wpp + ((size_t)(nh * 32 + 16 + l15) * 256 + l4 * 8);

    const int ih0 = 4 * hb - 1;

    for (int cb = 0; cb < 8; ++cb) {
        __syncthreads();
#pragma unroll
        for (int j = 0; j < 5; ++j) {
            const int jj  = wv + j * 4;
            const int row = jj >> 2, cig = jj & 3;
            const int ih  = ih0 + row;
            const int ihc = ih < 0 ? 0 : (ih > 111 ? 111 : ih);
            const float* xr = xb + ((size_t)(cb * 32 + cig * 8) * HIN + ihc) * WIN_;
            const bool rowin = (ih >= 0) && (ih < HIN);
#pragma unroll
            for (int p = 0; p < 2; ++p) {
                const int col = lane + p * 64;
                if (col < 113) {
                    const int iw  = col - 1;
                    const int iwc = iw < 0 ? 0 : iw;
                    const bool inb = rowin && (iw >= 0);
                    unsigned pk[4];
#pragma unroll
                    for (int q = 0; q < 4; ++q) {
                        float v0 = xr[(size_t)(2 * q) * HIN * WIN_ + iwc];
                        float v1 = xr[(size_t)(2 * q + 1) * HIN * WIN_ + iwc];
                        v0 = inb ? v0 : 0.f;
                        v1 = inb ? v1 : 0.f;
                        union { float f; unsigned u; } c0, c1; c0.f = v0; c1.f = v1;
                        unsigned u0 = c0.u + 0x7fffu + ((c0.u >> 16) & 1u);
                        unsigned u1 = c1.u + 0x7fffu + ((c1.u >> 16) & 1u);
                        pk[q] = (u0 >> 16) | (u1 & 0xffff0000u);
                    }
                    int ba = (row * 120 + col) * 64 + cig * 16;
                    ba ^= ((col >> 1) & 7) << 4;
                    *(uint4*)((char*)in_lds + ba) = make_uint4(pk[0], pk[1], pk[2], pk[3]);
                }
            }
        }
        __syncthreads();

        const int rowb = (2 * r) * 7680;
#pragma unroll
        for (int kh = 0; kh < 3; ++kh) {
            const int rb = rowb + kh * 7680;
#pragma unroll
            for (int kw = 0; kw < 3; ++kw) {
                const int tap = kh * 3 + kw;
                const bf16x8 bf0 = *(const bf16x8*)(bptr0 + tap * 16384 + cb * 32);
                const bf16x8 bf1 = *(const bf16x8*)(bptr1 + tap * 16384 + cb * 32);
#pragma unroll
                for (int mt = 0; mt < 4; ++mt) {
                    const bf16x8 af = *(const bf16x8*)((const char*)in_lds + (rb + a_off[mt][kw]));
                    acc[mt][0] = __builtin_amdgcn_mfma_f32_16x16x32_bf16(af, bf0, acc[mt][0], 0, 0, 0);
                    acc[mt][1] = __builtin_amdgcn_mfma_f32_16x16x32_bf16(af, bf1, acc[mt][1], 0, 0, 0);
                }
            }
        }
    }

    const int cout0 = nh * 32 + l15;
    const int cout1 = cout0 + 16;
    const float sc0 = gamma[cout0] * rsqrtf(var[cout0] + 1e-5f);
    const float bb0 = beta[cout0] - mean[cout0] * sc0;
    const float sc1 = gamma[cout1] * rsqrtf(var[cout1] + 1e-5f);
    const float bb1 = beta[cout1] - mean[cout1] * sc1;

    float yv[4][2][4];
    float ssr[4][4];
#pragma unroll
    for (int mt = 0; mt < 4; ++mt) {
#pragma unroll
        for (int reg = 0; reg < 4; ++reg) {
            float y0 = fmaxf(fmaf(acc[mt][0][reg], sc0, bb0), 0.f);
            float y1 = fmaxf(fmaf(acc[mt][1][reg], sc1, bb1), 0.f);
            yv[mt][0][reg] = y0; yv[mt][1][reg] = y1;
            float ss = y0 * y0 + y1 * y1;
            ss += __shfl_xor(ss, 1);
            ss += __shfl_xor(ss, 2);
            ss += __shfl_xor(ss, 4);
            ss += __shfl_xor(ss, 8);
            ssr[mt][reg] = ss;
        }
    }
    if (l15 == 0) {
#pragma unroll
        for (int mt = 0; mt < 4; ++mt)
#pragma unroll
            for (int reg = 0; reg < 4; ++reg)
                sq[r][nh][mt * 16 + l4 * 4 + reg] = ssr[mt][reg];
    }
    __syncthreads();

    const int h = 2 * hb + r;
    unsigned short* fdst = frames + (size_t)bt * FRSZE + (size_t)(h + 4) * WPD * CH;
#pragma unroll
    for (int mt = 0; mt < 4; ++mt) {
#pragma unroll
        for (int reg = 0; reg < 4; ++reg) {
            const int c = mt * 16 + l4 * 4 + reg;
            if (c < 56) {
                const float tot = sq[r][0][c] + sq[r][1][c];
                const float inv = rsqrtf(tot + 1e-6f);
                unsigned short* dp = fdst + (size_t)(c + 4) * CH;
                dp[cout0] = f2bf(yv[mt][0][reg] * inv);
                dp[cout1] = f2bf(yv[mt][1][reg] * inv);
            }
        }
    }
}

// ---------------------------------------------------------------------------
// Pad-fill: zeros for the 6 temporal-pad (t,l) slabs.
// ---------------------------------------------------------------------------
__global__ __launch_bounds__(64) void pad_k(float* __restrict__ out)
{
    const int lane = threadIdx.x;
    const int h = blockIdx.x;
    const int p = blockIdx.y;          // 0..5
    const int b = blockIdx.z;
    const int PT[6] = {0, 0, 1, 6, 7, 7};
    const int PL[6] = {0, 1, 0, 4, 3, 4};
    const int t = PT[p], l = PL[p];
    float* ob = out + (size_t)((b * TSEG + t) * HO + h) * (WO * 405) + l * 81;
#pragma unroll 4
    for (int w = 0; w < 56; ++w) {
        float* orow = ob + (size_t)w * 405;
        orow[lane] = 0.f;
        if (lane < 17) orow[lane + 64] = 0.f;
    }
}

// ---------------------------------------------------------------------------
// Kernel 2 (R10): f-grouped correlation.
// Block (b, f, h) = 256 thr (4 waves): stage the 9 Z-rows (h..h+8) of frame
// f ONCE into LDS (72 KB, XOR-swizzled). All (t,l) units with t+l-2 == f and
// this h consume it: wave w -> (l=w, t=f+2-w); wave 0 also (l=4, t=f-2).
// B-traffic drops 610 MB -> 129 MB guaranteed.
// Transposed MFMA (A=Z, B=Y => C[zc][w], col=lane&15=w): each lane owns whole
// output rows; band extraction via a per-wave 504-float mini-slab.
// LDS total 81792 B -> 2 blocks/CU. One barrier per block.
// ---------------------------------------------------------------------------
__global__ __launch_bounds__(256) void corr_f_k(
    const unsigned short* __restrict__ frames, float* __restrict__ out)
{
    __shared__ unsigned short zl[9 * 4096];   // 73,728 B
    __shared__ float so[4][504];              //  8,064 B

    const int tid  = threadIdx.x;
    const int lane = tid & 63;
    const int wv   = tid >> 6;
    const int l15  = lane & 15;
    const int l4   = lane >> 4;
    const int w7   = lane / 9;                // 0..7 (lane 63 -> 7, idle at store)
    const int v9   = lane - w7 * 9;           // 0..8

    const int h = blockIdx.x;                 // 0..55
    const int f = blockIdx.y;                 // 0..7  (B-frame index)
    const int b = blockIdx.z;

    // ---- stage Z rows h..h+8 of frame (b,f) into swizzled LDS ----
    const unsigned short* zb = frames + (size_t)(b * TSEG + f) * FRSZE
                             + (size_t)h * (WPD * CH);
#pragma unroll
    for (int k = 0; k < 18; ++k) {
        const int e   = tid + k * 256;        // < 4608
        const int row = e >> 9;
        const int c   = e & 511;
        const uint4 val = *(const uint4*)(zb + (size_t)row * 4096 + c * 8);
        const int ba = row * 8192 + ((c * 16) ^ (((c >> 3) & 7) << 4));
        *(uint4*)((char*)zl + ba) = val;
    }
    __syncthreads();

    // Z-frag read offsets (A-operand): row px = n*16+l15, k-chunk = hf*32+l4*8
    int roff[4][2];
#pragma unroll
    for (int n = 0; n < 4; ++n) {
        const int px = n * 16 + l15;
#pragma unroll
        for (int hf = 0; hf < 2; ++hf)
            roff[n][hf] = (px * 128 + hf * 64 + l4 * 16) ^ ((px & 7) << 4);
    }

    const int PM[7] = {0, 0, 1, 1, 2, 2, 3};
    const int PN[7] = {0, 1, 1, 2, 2, 3, 3};
    float* sw = so[wv];

    for (int pass = 0; pass < 2; ++pass) {
        if (pass == 1 && wv != 0) break;
        const int l = (pass == 0) ? wv : 4;
        const int t = f + 2 - l;
        if (t < 0 || t > 7) continue;
        const int bt = b * TSEG + t;

        // Y fragments (B-operand): col w = m*16+l15, k = hf*32+l4*8
        const unsigned short* yb = frames + (size_t)bt * FRSZE
                                 + (size_t)(h + 4) * (WPD * CH);
        bf16x8 yf[4][2];
#pragma unroll
        for (int m = 0; m < 4; ++m) {
            int wc = (m << 4) + l15; if (wc > 55) wc = 55;  // clamp, masked later
            const unsigned short* ap = yb + (size_t)(wc + 4) * CH + (l4 << 3);
            yf[m][0] = *(const bf16x8*)(ap);
            yf[m][1] = *(const bf16x8*)(ap + 32);
        }

        float* ob = out + (size_t)(bt * HO + h) * (WO * 405) + l * 81;

#pragma unroll
        for (int u = 0; u < 9; ++u) {
            const char* rb = (const char*)zl + u * 8192;
            bf16x8 zf[4][2];
#pragma unroll
            for (int n = 0; n < 4; ++n) {
                zf[n][0] = *(const bf16x8*)(rb + roff[n][0]);
                zf[n][1] = *(const bf16x8*)(rb + roff[n][1]);
            }

            f32x4 acc[7];
#pragma unroll
            for (int i = 0; i < 7; ++i) acc[i] = (f32x4){0.f, 0.f, 0.f, 0.f};
#pragma unroll
            for (int i = 0; i < 7; ++i) {
                acc[i] = __builtin_amdgcn_mfma_f32_16x16x32_bf16(zf[PN[i]][0], yf[PM[i]][0], acc[i], 0, 0, 0);
                acc[i] = __builtin_amdgcn_mfma_f32_16x16x32_bf16(zf[PN[i]][1], yf[PM[i]][1], acc[i], 0, 0, 0);
            }

            // extraction: C[zc][w], zc = PN*16 + l4*4 + reg, w = PM*16 + l15
#pragma unroll
            for (int i = 0; i < 7; ++i) {
                const int w = (PM[i] << 4) + l15;
#pragma unroll
                for (int reg = 0; reg < 4; ++reg) {
                    const int zc = (PN[i] << 4) + (l4 << 2) + reg;
                    const int v  = zc - w;
                    if (w < 56 && (unsigned)v <= 8u)
                        sw[w * 9 + v] = acc[i][reg];
                }
            }

            // store this u's 56x9 band block (lane63 idle)
            if (w7 < 7) {
                float* obu = ob + u * 9;
#pragma unroll
                for (int it = 0; it < 8; ++it) {
                    const int w = it * 7 + w7;
                    obu[(size_t)w * 405 + v9] = sw[w * 9 + v9];
                }
            }
        }
    }
}

// ---------------------------------------------------------------------------
extern "C" void kernel_launch(void* const* d_in, const int* in_sizes, int n_in,
                              void* d_out, int out_size, void* d_ws, size_t ws_size,
                              hipStream_t stream)
{
    const float* x     = (const float*)d_in[0];
    const float* wgt   = (const float*)d_in[1];
    const float* gamma = (const float*)d_in[2];
    const float* beta  = (const float*)d_in[3];
    const float* mean  = (const float*)d_in[4];
    const float* var   = (const float*)d_in[5];
    float* out = (float*)d_out;

    unsigned short* wpp    = (unsigned short*)d_ws;
    unsigned short* frames = wpp + FR_U;

    if (ws_size < WS_TOTAL_BYTES) return;

    hipMemsetAsync(d_ws, 0, WS_TOTAL_BYTES, stream);
    wprep_k<<<dim3(576), 256, 0, stream>>>(wgt, wpp);
    conv_mfma_k<<<dim3(28, NBT), 256, 0, stream>>>(x, wpp, gamma, beta, mean, var, frames);
    pad_k<<<dim3(56, 6, NBC), 64, 0, stream>>>(out);
    corr_f_k<<<dim3(56, TSEG, NBC), 256, 0, stream>>>(frames, out);
}